// Round 6
// baseline (154.730 us; speedup 1.0000x reference)
//
#include <hip/hip_runtime.h>
#include <stdint.h>

#define N_BASES 5
#define WELEM (128 * 128 * 3 * 3) /* 147456 per base */

typedef __attribute__((ext_vector_type(4))) float f32x4;
typedef __attribute__((ext_vector_type(8))) short bf16x8;

__device__ __forceinline__ unsigned short f2bf(float v) {
  union { float f; uint32_t u; } un;
  un.f = v;
  uint32_t r = un.u + 0x7FFFu + ((un.u >> 16) & 1u);
  return (unsigned short)(r >> 16);
}

__device__ __forceinline__ void glds16(const void* g, void* l) {
  __builtin_amdgcn_global_load_lds(
      (const __attribute__((address_space(1))) void*)g,
      (__attribute__((address_space(3))) void*)l, 16, 0, 0);
}

// ---- kernel 1 (fused): blocks 0..1855 = x NCHW fp32 -> padded NHWC bf16;
//      blocks 1856..2175 = per-(base,chunk) |w| partial sums.
__global__ __launch_bounds__(256) void prep_fused(
    const float* __restrict__ x, const float* __restrict__ w,
    unsigned short* __restrict__ xp, float* __restrict__ csum_part) {
  int bi = blockIdx.x;
  if (bi >= 1856) {
    int id = bi - 1856;
    int n = id >> 6;
    int chunk = id & 63;
    const f32x4* wb = (const f32x4*)(w + (size_t)n * WELEM + chunk * 2304);
    float s = 0.f;
    for (int i = threadIdx.x; i < 576; i += 256) {
      f32x4 v = wb[i];
      s += fabsf(v.x) + fabsf(v.y) + fabsf(v.z) + fabsf(v.w);
    }
    #pragma unroll
    for (int off = 32; off > 0; off >>= 1) s += __shfl_down(s, off);
    __shared__ float red[4];
    if ((threadIdx.x & 63) == 0) red[threadIdx.x >> 6] = s;
    __syncthreads();
    if (threadIdx.x == 0) csum_part[id] = red[0] + red[1] + red[2] + red[3];
    return;
  }
  int b = bi / 58;
  int hp = bi - b * 58;
  unsigned short* dst = xp + ((size_t)b * 58 + hp) * 58 * 128;
  int gh = hp - 1;
  if ((unsigned)gh >= 56u) {  // full pad row
    uint4 ones = make_uint4(0x3F803F80u, 0x3F803F80u, 0x3F803F80u, 0x3F803F80u);
    for (int i = threadIdx.x; i < 928; i += 256) ((uint4*)dst)[i] = ones;
    return;
  }
  __shared__ unsigned short tile[128][61];
  const float* src = x + ((size_t)b * 128 * 56 + gh) * 56;
  for (int i = threadIdx.x; i < 128 * 14; i += 256) {
    int c = i / 14;
    int k = i - c * 14;
    f32x4 v = *(const f32x4*)(src + (size_t)c * 3136 + k * 4);
    tile[c][1 + 4 * k + 0] = f2bf(v.x);
    tile[c][1 + 4 * k + 1] = f2bf(v.y);
    tile[c][1 + 4 * k + 2] = f2bf(v.z);
    tile[c][1 + 4 * k + 3] = f2bf(v.w);
  }
  if (threadIdx.x < 128) {
    tile[threadIdx.x][0] = 0x3F80;
    tile[threadIdx.x][57] = 0x3F80;
  }
  __syncthreads();
  for (int i = threadIdx.x; i < 928; i += 256) {
    int wp = i >> 4;
    int c8 = i & 15;
    union { uint4 q; unsigned short h[8]; } u;
    #pragma unroll
    for (int j = 0; j < 8; ++j) u.h[j] = tile[c8 * 8 + j][wp];
    *(uint4*)(dst + (size_t)wp * 128 + c8 * 8) = u.q;
  }
}

// ---- kernel 2: W_eff -> bf16 in flat stage layout:
// stage s = t*4 + kb (kb = 32-ch block) holds [o=0..127][ch=0..31]:
// element (o, i, t) -> wq2[s*4096 + o*32 + (i&31)]. DMA = flat lane-linear copy.
__global__ __launch_bounds__(256) void binweight_kernel(
    const float* __restrict__ w, const float* __restrict__ csum_part,
    const float* __restrict__ scales, unsigned short* __restrict__ wq2) {
  __shared__ float parts[320];
  __shared__ float coef[N_BASES];
  for (int i = threadIdx.x; i < 320; i += 256) parts[i] = csum_part[i];
  __syncthreads();
  if (threadIdx.x < N_BASES) {
    float s = 0.f;
    #pragma unroll 8
    for (int k = 0; k < 64; ++k) s += parts[threadIdx.x * 64 + k];
    coef[threadIdx.x] = scales[threadIdx.x] * s * (1.0f / (float)WELEM);
  }
  __syncthreads();
  int f = blockIdx.x * 256 + threadIdx.x;  // f = o*1152 + i*9 + t
  float s = 0.f;
  #pragma unroll
  for (int n = 0; n < N_BASES; ++n) {
    float cn = coef[n];
    float v = w[n * WELEM + f];
    s += (v > 0.f) ? cn : ((v < 0.f) ? -cn : 0.f);
  }
  int o = f / 1152;
  int rem = f - o * 1152;
  int i = rem / 9;
  int t = rem - i * 9;
  int s_idx = t * 4 + (i >> 5);
  wq2[(size_t)s_idx * 4096 + o * 32 + (i & 31)] = f2bf(s);
}

// ---- kernel 3: implicit-GEMM conv, TRIPLE-buffered B stages.
// Block: 2 imgs x (4h x 16w) x 128 cout, 256 thr = 4 waves;
// wave (img = w>>1, nh = w&1) computes M=64 x N=64.
// 36 phases (t*4+kb). Phase p: vmcnt(2) (own DMA(p) landed; DMA(p+1) may fly),
// s_barrier (all waves' DMA(p) visible + phase p-1 reads done), issue
// DMA(p+2) into buf (p-1)%3 (readers finished), 8 ds_read_b128 + 16 MFMA.
// Buf being read (p%3) is never a DMA target => no overwrite race.
// Tail p=35: vmcnt(0) (dma(35) issued at p=33, already landed). ----
__global__ __launch_bounds__(256, 2) void conv_kernel(
    const unsigned short* __restrict__ xp, const unsigned short* __restrict__ wq2,
    float* __restrict__ out) {
  __shared__ unsigned short patch[27648];  // 2 img x 108 sp x 128 ch (55.3 KB)
  __shared__ unsigned short btile[12288];  // 3 x (128 o x 32 ch) (24.6 KB)

  const int tid = threadIdx.x;
  const int blk = blockIdx.x;
  const int pair = blk & 15;      // imgs pair, pair+16
  const int tileIdx = blk >> 4;   // 0..55 = hi*4 + wi
  const int hi = tileIdx >> 2;
  const int wi = tileIdx & 3;
  const int h0 = hi * 4;
  const int w0 = (wi == 3) ? 40 : wi * 16;

  const int lane = tid & 63;
  const int wave = tid >> 6;
  const int img = wave >> 1;
  const int nh = wave & 1;
  const int l15 = lane & 15;
  const int quad = lane >> 4;

  // ---- B DMA: stage s (8 KB) -> btile[(s%3)*4096..], flat lane-linear ----
  const unsigned short* wq_base = wq2 + wave * 1024 + lane * 8;
  unsigned short* lds_base = &btile[wave * 1024];
  auto dma = [&](int s) {
    const unsigned short* g = wq_base + (size_t)s * 4096;
    unsigned short* l = lds_base + (s % 3) * 4096;
    glds16(g, l);
    glds16(g + 512, l + 512);
  };

  dma(0);
  dma(1);

  // ---- stage patch: 2 x 108 sp (6 rows x 18 px) x 16 chunks, XOR-swizzled ----
  const size_t rowstride = 58 * 128;
  for (int i = tid; i < 3456; i += 256) {
    int im = i / 1728;
    int r = i - im * 1728;
    int sp = r >> 4;
    int c16 = r & 15;
    int ph = sp / 18;
    int pw = sp - ph * 18;
    int b = pair + im * 16;
    const unsigned short* gp = xp + ((size_t)b * 58 + (h0 + ph)) * rowstride +
                               (size_t)(w0 + pw) * 128 + c16 * 8;
    uint4 v = *(const uint4*)gp;
    *(uint4*)&patch[im * 13824 + sp * 128 + ((c16 ^ (sp & 7)) << 3)] = v;
  }
  __syncthreads();  // full drain: patch stores AND DMA(0)/DMA(1) visible

  f32x4 acc[4][4];
  #pragma unroll
  for (int mf = 0; mf < 4; ++mf)
    #pragma unroll
    for (int nf = 0; nf < 4; ++nf) acc[mf][nf] = (f32x4)0.f;

  const unsigned short* pb = &patch[img * 13824];
  const unsigned short* bt = &btile[(nh * 64) * 32 + quad * 8];

  #pragma unroll
  for (int p = 0; p < 36; ++p) {  // p = t*4 + kb
    const int t = p >> 2;
    const int kb = p & 3;
    const int kh = t / 3;
    const int kw = t - kh * 3;

    // Own DMA(p) landed: allow 2 outstanding loads (= DMA(p+1)); tail: 0.
    if (p < 35)
      __builtin_amdgcn_s_waitcnt(0x0F72);  // vmcnt(2)
    else
      __builtin_amdgcn_s_waitcnt(0x0F70);  // vmcnt(0)
    __builtin_amdgcn_s_barrier();  // all waves: DMA(p) visible, p-1 reads done
    if (p + 2 < 36) dma(p + 2);    // writes buf (p-1)%3 — safe, readers done

    bf16x8 af[4], bf[4];
    #pragma unroll
    for (int mf = 0; mf < 4; ++mf) {
      int sp = (mf + kh) * 18 + (l15 + kw);
      af[mf] = *(const bf16x8*)&pb[sp * 128 + (((kb * 4 + quad) ^ (sp & 7)) << 3)];
    }
    const unsigned short* bs = bt + (p % 3) * 4096;
    #pragma unroll
    for (int nf = 0; nf < 4; ++nf)
      bf[nf] = *(const bf16x8*)(bs + (nf * 16 + l15) * 32);
    #pragma unroll
    for (int mf = 0; mf < 4; ++mf)
      #pragma unroll
      for (int nf = 0; nf < 4; ++nf)
        acc[mf][nf] = __builtin_amdgcn_mfma_f32_16x16x32_bf16(
            af[mf], bf[nf], acc[mf][nf], 0, 0, 0);
  }

  // ---- epilogue: D row = quad*4+r = w-offset, col = l15 = cout-low.
  // lane's f32x4 = w0+quad*4 .. +3 at h = h0+mf: full 64-B sectors. ----
  const int b = pair + img * 16;
  #pragma unroll
  for (int mf = 0; mf < 4; ++mf) {
    int h = h0 + mf;
    #pragma unroll
    for (int nf = 0; nf < 4; ++nf) {
      int o = nh * 64 + nf * 16 + l15;
      float* p = out + (((size_t)b * 128 + o) * 56 + h) * 56 + w0 + quad * 4;
      *(f32x4*)p = acc[mf][nf];
    }
  }
}

extern "C" void kernel_launch(void* const* d_in, const int* in_sizes, int n_in,
                              void* d_out, int out_size, void* d_ws, size_t ws_size,
                              hipStream_t stream) {
  const float* x = (const float*)d_in[0];       // [32,128,56,56]
  const float* w = (const float*)d_in[1];       // [5,128,128,3,3]
  const float* scales = (const float*)d_in[2];  // [5]
  float* out = (float*)d_out;                   // [32,128,56,56]

  float* csum_part = (float*)d_ws;                                    // 320 floats
  unsigned short* wq2 = (unsigned short*)((char*)d_ws + 4096);        // 36*4096 bf16
  unsigned short* xpad = (unsigned short*)((char*)d_ws + 512 * 1024); // 32*58*58*128 bf16

  prep_fused<<<1856 + 320, 256, 0, stream>>>(x, w, xpad, csum_part);
  binweight_kernel<<<576, 256, 0, stream>>>(w, csum_part, scales, wq2);
  conv_kernel<<<56 * 16, 256, 0, stream>>>(xpad, wq2, out);
}